// Round 1
// baseline (106.475 us; speedup 1.0000x reference)
//
#include <hip/hip_runtime.h>

// Deformable 3x3 local correlation (CREStereo-style) on MI355X.
// Shapes: left/right (2,128,64,256) f32, extra_offset (2,18,64,256) f32,
// out (2,72,64,256) f32.  GROUPS=8, cg=16, S=9.

#define NB 2
#define CC 128
#define HH 64
#define WW 256
#define GG 8
#define CG 16
#define SS 9
#define HW (HH * WW)

__global__ __launch_bounds__(WW) void corr_kernel(
    const float* __restrict__ left, const float* __restrict__ right,
    const float* __restrict__ eo, float* __restrict__ out)
{
    const int w = threadIdx.x;
    const int bid = blockIdx.x;
    const int g = bid & (GG - 1);          // group
    const int h = (bid >> 3) & (HH - 1);   // row
    const int n = bid >> 9;                // batch

    const int pix = h * WW + w;
    const float* eo_base = eo + (size_t)n * SS * 2 * HW + pix;

    int off00[SS], off01[SS], off10[SS], off11[SS];
    float wa[SS], wb[SS], wc[SS], wd[SS];

#pragma unroll
    for (int s = 0; s < SS; ++s) {
        // base 3x3 window offsets, meshgrid 'ij': x = s/3 - 1, y = s%3 - 1
        float bx = (float)(s / 3 - 1);
        float by = (float)(s % 3 - 1);
        // extra_offset[n, 2*s+0, h, w] = x-offset, [n, 2*s+1, h, w] = y-offset
        float x = bx + eo_base[(2 * s) * HW] + (float)w;
        float y = by + eo_base[(2 * s + 1) * HW] + (float)h;

        float x0f = floorf(x), y0f = floorf(y);
        float x1f = x0f + 1.0f, y1f = y0f + 1.0f;
        float fx0 = x - x0f, fx1 = x1f - x;   // frac weights
        float fy0 = y - y0f, fy1 = y1f - y;

        int x0 = (int)x0f, y0 = (int)y0f;
        int x1 = x0 + 1,   y1 = y0 + 1;
        bool vx0 = (x0 >= 0) && (x0 < WW);
        bool vx1 = (x1 >= 0) && (x1 < WW);
        bool vy0 = (y0 >= 0) && (y0 < HH);
        bool vy1 = (y1 >= 0) && (y1 < HH);
        int cx0 = min(max(x0, 0), WW - 1), cx1 = min(max(x1, 0), WW - 1);
        int cy0 = min(max(y0, 0), HH - 1), cy1 = min(max(y1, 0), HH - 1);

        // zero-pad semantics: out-of-range tap contributes 0 (weight zeroed,
        // index clamped so the load stays in-bounds)
        wa[s] = (vx0 && vy0) ? fx1 * fy1 : 0.0f;
        wb[s] = (vx0 && vy1) ? fx1 * fy0 : 0.0f;
        wc[s] = (vx1 && vy0) ? fx0 * fy1 : 0.0f;
        wd[s] = (vx1 && vy1) ? fx0 * fy0 : 0.0f;
        off00[s] = cy0 * WW + cx0;
        off01[s] = cy1 * WW + cx0;
        off10[s] = cy0 * WW + cx1;
        off11[s] = cy1 * WW + cx1;
    }

    float acc[SS];
#pragma unroll
    for (int s = 0; s < SS; ++s) acc[s] = 0.0f;

    const float* lptr = left  + ((size_t)(n * CC + g * CG)) * HW + pix;
    const float* rbase = right + ((size_t)(n * CC + g * CG)) * HW;

    for (int c = 0; c < CG; ++c) {
        float lv = lptr[c * HW];
        const float* rp = rbase + (size_t)c * HW;
#pragma unroll
        for (int s = 0; s < SS; ++s) {
            float v = wa[s] * rp[off00[s]] + wb[s] * rp[off01[s]]
                    + wc[s] * rp[off10[s]] + wd[s] * rp[off11[s]];
            acc[s] += lv * v;
        }
    }

    float* obase = out + ((size_t)(n * GG + g) * SS) * HW + pix;
#pragma unroll
    for (int s = 0; s < SS; ++s)
        obase[s * HW] = acc[s] * (1.0f / CG);
}

extern "C" void kernel_launch(void* const* d_in, const int* in_sizes, int n_in,
                              void* d_out, int out_size, void* d_ws, size_t ws_size,
                              hipStream_t stream) {
    const float* left  = (const float*)d_in[0];
    const float* right = (const float*)d_in[1];
    const float* eo    = (const float*)d_in[2];
    float* out = (float*)d_out;

    dim3 grid(NB * HH * GG);   // 1024 blocks: (n, h, group)
    dim3 block(WW);            // one thread per w
    corr_kernel<<<grid, block, 0, stream>>>(left, right, eo, out);
}

// Round 2
// 72.591 us; speedup vs baseline: 1.4668x; 1.4668x over previous
//
#include <hip/hip_runtime.h>

// Deformable 3x3 local correlation, LDS-staged gathers.
// left/right (2,128,64,256) f32, extra_offset (2,18,64,256) f32,
// out (2,72,64,256) f32. GROUPS=8, cg=16, S=9.

#define NB 2
#define CC 128
#define HH 64
#define WW 256
#define GG 8
#define CG 16
#define SS 9
#define HW (HH * WW)
#define RWIN 8                  // stage rows h-RWIN .. h+RWIN+1
#define NRMAX (2 * RWIN + 2)    // 18
#define LSTR 260                // padded LDS row stride (floats): 1040B, 16B-aligned

__global__ __launch_bounds__(256, 4) void corr_kernel(
    const float* __restrict__ left, const float* __restrict__ right,
    const float* __restrict__ eo, float* __restrict__ out)
{
    __shared__ float smem[NRMAX * LSTR];   // 18.7 KB

    const int w = threadIdx.x;
    const int bid = blockIdx.x;
    const int g = bid & (GG - 1);
    const int h = (bid >> 3) & (HH - 1);
    const int n = bid >> 9;

    const int row0 = max(0, h - RWIN);
    const int row1 = min(HH - 1, h + RWIN + 1);
    const int nrows = row1 - row0 + 1;

    const int pix = h * WW + w;
    const float* eo_base = eo + (size_t)n * SS * 2 * HW + pix;

    float wt[SS][4];
    int lofs[SS][4];               // LDS byte offsets (window-relative; OOW if bad)
    unsigned long long badmask = 0ull;

#pragma unroll
    for (int s = 0; s < SS; ++s) {
        const float bx = (float)(s / 3 - 1);
        const float by = (float)(s % 3 - 1);
        const float x = bx + eo_base[(2 * s) * HW] + (float)w;
        const float y = by + eo_base[(2 * s + 1) * HW] + (float)h;

        const float x0f = floorf(x), y0f = floorf(y);
        const float fx0 = x - x0f, fx1 = 1.0f - fx0;
        const float fy0 = y - y0f, fy1 = 1.0f - fy0;

        const int x0 = (int)x0f, y0 = (int)y0f;
        const int x1 = x0 + 1,   y1 = y0 + 1;
        const bool vx0 = (unsigned)x0 < (unsigned)WW;
        const bool vx1 = (unsigned)x1 < (unsigned)WW;
        const bool vy0 = (unsigned)y0 < (unsigned)HH;
        const bool vy1 = (unsigned)y1 < (unsigned)HH;

        wt[s][0] = (vx0 && vy0) ? fx1 * fy1 : 0.0f;   // (x0,y0)
        wt[s][1] = (vx0 && vy1) ? fx1 * fy0 : 0.0f;   // (x0,y1)
        wt[s][2] = (vx1 && vy0) ? fx0 * fy1 : 0.0f;   // (x1,y0)
        wt[s][3] = (vx1 && vy1) ? fx0 * fy0 : 0.0f;   // (x1,y1)

        const int cx0 = min(max(x0, 0), WW - 1), cx1 = min(max(x1, 0), WW - 1);
        const int cy0 = min(max(y0, 0), HH - 1), cy1 = min(max(y1, 0), HH - 1);

        lofs[s][0] = (((cy0 - row0) * LSTR) + cx0) * 4;
        lofs[s][1] = (((cy1 - row0) * LSTR) + cx0) * 4;
        lofs[s][2] = (((cy0 - row0) * LSTR) + cx1) * 4;
        lofs[s][3] = (((cy1 - row0) * LSTR) + cx1) * 4;

        // tap outside the staged window (|eo| huge) -> global fallback
        const bool b0 = (cy0 < row0) || (cy0 > row1);
        const bool b1 = (cy1 < row0) || (cy1 > row1);
        if (b0) badmask |= (1ull << (s * 4 + 0)) | (1ull << (s * 4 + 2));
        if (b1) badmask |= (1ull << (s * 4 + 1)) | (1ull << (s * 4 + 3));
    }

    float acc[SS];
#pragma unroll
    for (int s = 0; s < SS; ++s) acc[s] = 0.0f;

    const float* lp = left  + (size_t)(n * CC + g * CG) * HW + pix;
    const float* rp = right + (size_t)(n * CC + g * CG) * HW;
    const char* smemb = (const char*)smem;

    for (int c = 0; c < CG; ++c, rp += HW) {
        __syncthreads();
        // stage rows [row0, row1] of this channel plane; one wave per row,
        // 64 lanes x float4 = 256 floats = exactly one row (coalesced).
#pragma unroll
        for (int p = 0; p < 5; ++p) {
            const int r = p * 4 + (w >> 6);            // wave-uniform row id
            if (r < nrows) {
                const int col = (w & 63) << 2;
                *(float4*)&smem[r * LSTR + col] =
                    *(const float4*)(rp + (row0 + r) * WW + col);
            }
        }
        __syncthreads();

        const float lv = lp[(size_t)c * HW];

        if (__builtin_expect(badmask == 0ull, 1)) {
#pragma unroll
            for (int s = 0; s < SS; ++s) {
                float v = wt[s][0] * *(const float*)(smemb + lofs[s][0])
                        + wt[s][1] * *(const float*)(smemb + lofs[s][1])
                        + wt[s][2] * *(const float*)(smemb + lofs[s][2])
                        + wt[s][3] * *(const float*)(smemb + lofs[s][3]);
                acc[s] += lv * v;
            }
        } else {
            // rare: some tap fell outside the staged window
#pragma unroll
            for (int s = 0; s < SS; ++s) {
                float v = 0.0f;
#pragma unroll
                for (int t = 0; t < 4; ++t) {
                    const int lb = lofs[s][t];
                    float xv;
                    if ((badmask >> (s * 4 + t)) & 1ull) {
                        const int li = lb / 4;                      // exact (lb = 4*la)
                        const int cyrel = (li >= 0) ? (li / LSTR)
                                                    : -((-li + LSTR - 1) / LSTR);
                        const int cx = li - cyrel * LSTR;           // in [0,255]
                        xv = rp[(row0 + cyrel) * WW + cx];          // always in-plane
                    } else {
                        xv = *(const float*)(smemb + lb);
                    }
                    v += wt[s][t] * xv;
                }
                acc[s] += lv * v;
            }
        }
    }

    float* ob = out + ((size_t)(n * GG + g) * SS) * HW + pix;
#pragma unroll
    for (int s = 0; s < SS; ++s)
        ob[s * HW] = acc[s] * (1.0f / CG);
}

extern "C" void kernel_launch(void* const* d_in, const int* in_sizes, int n_in,
                              void* d_out, int out_size, void* d_ws, size_t ws_size,
                              hipStream_t stream) {
    const float* left  = (const float*)d_in[0];
    const float* right = (const float*)d_in[1];
    const float* eo    = (const float*)d_in[2];
    float* out = (float*)d_out;
    (void)d_ws; (void)ws_size; (void)in_sizes; (void)n_in; (void)out_size;

    dim3 grid(NB * HH * GG);   // (n, h, group)
    dim3 block(WW);            // one thread per w
    corr_kernel<<<grid, block, 0, stream>>>(left, right, eo, out);
}

// Round 3
// 64.078 us; speedup vs baseline: 1.6616x; 1.1329x over previous
//
#include <hip/hip_runtime.h>

// Deformable 3x3 local correlation, LDS-staged gathers, immediate-offset taps.
// left/right (2,128,64,256) f32, extra_offset (2,18,64,256) f32,
// out (2,72,64,256) f32. GROUPS=8, cg=16, S=9.

#define NB 2
#define CC 128
#define HH 64
#define WW 256
#define GG 8
#define CG 16
#define SS 9
#define HW (HH * WW)
#define RWIN 8
#define NDATA (2 * RWIN + 2)        // max staged data rows = 18
#define ROWDW 264                   // LDS row stride in dwords (16B-aligned, +8 bank rot)
#define B0 4                        // data starts at dword 4 of each row slot
#define SMEMDW (B0 + 20 * ROWDW)    // 20 row slots (1 top guard + 18 data + 1 bottom guard)

__global__ __launch_bounds__(256) void corr_kernel(
    const float* __restrict__ left, const float* __restrict__ right,
    const float* __restrict__ eo, float* __restrict__ out)
{
    __shared__ float smem[SMEMDW];   // 21.1 KB

    const int w = threadIdx.x;
    const int bid = blockIdx.x;
    const int g = bid & (GG - 1);
    const int h = (bid >> 3) & (HH - 1);
    const int n = bid >> 9;

    const int row0 = max(0, h - RWIN);
    const int row1 = min(HH - 1, h + RWIN + 1);
    const int nrows = row1 - row0 + 1;

    // zero everything once: guard rows/cols must read as 0.0 (weight-0 taps land there)
    for (int i = w; i < SMEMDW; i += 256) smem[i] = 0.0f;

    const int pix = h * WW + w;
    const float* eob = eo + (size_t)n * SS * 2 * HW + pix;

    int lbase[SS];
    float wA[SS], wB[SS], wC[SS], wD[SS];
    int badmask = 0;

#pragma unroll
    for (int s = 0; s < SS; ++s) {
        const float x = (float)(s / 3 - 1) + eob[(2 * s) * HW] + (float)w;
        const float y = (float)(s % 3 - 1) + eob[(2 * s + 1) * HW] + (float)h;
        const float x0f = floorf(x), y0f = floorf(y);
        const float fx0 = x - x0f, fx1 = 1.0f - fx0;
        const float fy0 = y - y0f, fy1 = 1.0f - fy0;
        const int x0 = (int)x0f, y0 = (int)y0f;
        const int x1 = x0 + 1,   y1 = y0 + 1;
        const bool vx0 = (unsigned)x0 < (unsigned)WW;
        const bool vx1 = (unsigned)x1 < (unsigned)WW;
        const bool vy0 = (unsigned)y0 < (unsigned)HH;
        const bool vy1 = (unsigned)y1 < (unsigned)HH;

        wA[s] = (vx0 && vy0) ? fx1 * fy1 : 0.0f;   // (x0,y0) -> +0
        wB[s] = (vx1 && vy0) ? fx0 * fy1 : 0.0f;   // (x1,y0) -> +4B
        wC[s] = (vx0 && vy1) ? fx1 * fy0 : 0.0f;   // (x0,y1) -> +ROWDW*4
        wD[s] = (vx1 && vy1) ? fx0 * fy0 : 0.0f;   // (x1,y1) -> +ROWDW*4+4

        // shared base address; out-of-range components clamp into zeroed guard space
        const int xc = min(max(x0, -1), WW);            // [-1, 256]
        const int rr = min(max(y0 - row0 + 1, 0), NDATA); // [0, 18]
        lbase[s] = (B0 + rr * ROWDW + xc) * 4;

        // tap row valid in image but outside staged window -> global fallback
        if ((vy0 && (y0 < row0 || y0 > row1)) || (vy1 && (y1 < row0 || y1 > row1)))
            badmask |= 1 << s;
    }

    float acc[SS];
#pragma unroll
    for (int s = 0; s < SS; ++s) acc[s] = 0.0f;

    const float* lp = left  + (size_t)(n * CC + g * CG) * HW + pix;
    const float* rp = right + (size_t)(n * CC + g * CG) * HW;
    const char* sb = (const char*)smem;

    for (int c = 0; c < CG; ++c, rp += HW) {
        __syncthreads();
        // stage rows [row0,row1] into row slots 1..nrows; one wave per row,
        // 64 lanes x float4 = one full row, coalesced, 16B-aligned dest.
#pragma unroll
        for (int p = 0; p < 5; ++p) {
            const int r = p * 4 + (w >> 6);
            if (r < nrows) {
                const int col = (w & 63) << 2;
                *(float4*)&smem[B0 + (r + 1) * ROWDW + col] =
                    *(const float4*)(rp + (row0 + r) * WW + col);
            }
        }
        __syncthreads();

        const float lv = lp[(size_t)c * HW];

        if (__builtin_expect(badmask == 0, 1)) {
#pragma unroll
            for (int s = 0; s < SS; ++s) {
                const float* p = (const float*)(sb + lbase[s]);
                const float v = wA[s] * p[0] + wB[s] * p[1]
                              + wC[s] * p[ROWDW] + wD[s] * p[ROWDW + 1];
                acc[s] += lv * v;
            }
        } else {
            // ~never taken (needs |offset| > ~7 sigma); recompute from global
#pragma unroll
            for (int s = 0; s < SS; ++s) {
                const float x = (float)(s / 3 - 1) + eob[(2 * s) * HW] + (float)w;
                const float y = (float)(s % 3 - 1) + eob[(2 * s + 1) * HW] + (float)h;
                const float x0f = floorf(x), y0f = floorf(y);
                const float fx0 = x - x0f, fx1 = 1.0f - fx0;
                const float fy0 = y - y0f, fy1 = 1.0f - fy0;
                const int x0 = (int)x0f, y0 = (int)y0f;
                const int x1 = x0 + 1,   y1 = y0 + 1;
                const bool vx0 = (unsigned)x0 < (unsigned)WW;
                const bool vx1 = (unsigned)x1 < (unsigned)WW;
                const bool vy0 = (unsigned)y0 < (unsigned)HH;
                const bool vy1 = (unsigned)y1 < (unsigned)HH;
                const float a = (vx0 && vy0) ? fx1 * fy1 : 0.0f;
                const float b = (vx1 && vy0) ? fx0 * fy1 : 0.0f;
                const float cc2 = (vx0 && vy1) ? fx1 * fy0 : 0.0f;
                const float d = (vx1 && vy1) ? fx0 * fy0 : 0.0f;
                const int cx0 = min(max(x0, 0), WW - 1), cx1 = min(max(x1, 0), WW - 1);
                const int cy0 = min(max(y0, 0), HH - 1), cy1 = min(max(y1, 0), HH - 1);
                const float v = a * rp[cy0 * WW + cx0] + b * rp[cy0 * WW + cx1]
                              + cc2 * rp[cy1 * WW + cx0] + d * rp[cy1 * WW + cx1];
                acc[s] += lv * v;
            }
        }
    }

    float* ob = out + ((size_t)(n * GG + g) * SS) * HW + pix;
#pragma unroll
    for (int s = 0; s < SS; ++s)
        ob[s * HW] = acc[s] * (1.0f / CG);
}

extern "C" void kernel_launch(void* const* d_in, const int* in_sizes, int n_in,
                              void* d_out, int out_size, void* d_ws, size_t ws_size,
                              hipStream_t stream) {
    const float* left  = (const float*)d_in[0];
    const float* right = (const float*)d_in[1];
    const float* eo    = (const float*)d_in[2];
    float* out = (float*)d_out;
    (void)d_ws; (void)ws_size; (void)in_sizes; (void)n_in; (void)out_size;

    dim3 grid(NB * HH * GG);   // (n, h, group)
    dim3 block(WW);            // one thread per w
    corr_kernel<<<grid, block, 0, stream>>>(left, right, eo, out);
}

// Round 4
// 40.236 us; speedup vs baseline: 2.6463x; 1.5926x over previous
//
#include <hip/hip_runtime.h>
#include <stdint.h>

// Deformable 3x3 local correlation. h-tiled blocks, async double-buffered
// LDS staging via global_load_lds(16B), immediate-offset bilinear taps.
// left/right (2,128,64,256) f32, extra_offset (2,18,64,256) f32,
// out (2,72,64,256) f32. GROUPS=8, cg=16, S=9.

#define NB 2
#define CC 128
#define HH 64
#define WW 256
#define GG 8
#define CG 16
#define SS 9
#define HW (HH * WW)
#define TY 4                      // output rows per block
#define ROWDW 264                 // dwords per row slot (guards + 256 data + pad)
#define GUARD 4                   // data starts at dword 4 of a slot
#define NSLOT 23                  // 1 top guard + 21 data + 1 bottom guard
#define BUFDW (NSLOT * ROWDW)     // 6072 dwords per buffer (24.3 KB)

typedef __attribute__((address_space(3))) uint32_t lds_t;
typedef const __attribute__((address_space(1))) uint32_t glb_t;

// stage rows [row0, row0+nrows) of channel plane RPCH into buffer at BOFS_DW.
// One global_load_lds_dwordx4 per row per wave: wave-uniform LDS base,
// per-lane global src (lane*16B) -> 1024B = one full row.
#define STAGE(BOFS_DW, RPCH)                                                   \
  _Pragma("unroll")                                                            \
  for (int rep = 0; rep < 2; ++rep) {                                          \
    const int r = wv + rep * 16;                                               \
    if (r < nrows) {                                                           \
      const float* src = (RPCH) + (row0 + r) * WW + (lane << 2);               \
      lds_t* dst = (lds_t*)&smem[(BOFS_DW) + (sbase + r) * ROWDW + GUARD];     \
      __builtin_amdgcn_global_load_lds((glb_t*)src, dst, 16, 0, 0);            \
    }                                                                          \
  }

#define COMPUTE(BOFS, RPC)                                                     \
  if (__builtin_expect(badmask == 0, 1)) {                                     \
    _Pragma("unroll")                                                          \
    for (int s = 0; s < SS; ++s) {                                             \
      const float* p = (const float*)(sb + lbase[s]);                          \
      const float v = wA[s] * p[(BOFS)] + wB[s] * p[(BOFS) + 1]                \
                    + wC[s] * p[(BOFS) + ROWDW] + wD[s] * p[(BOFS) + ROWDW + 1]; \
      acc[s] += lv * v;                                                        \
    }                                                                          \
  } else {                                                                     \
    _Pragma("unroll")                                                          \
    for (int s = 0; s < SS; ++s) {                                             \
      const float x = (float)(s / 3 - 1) + eob[(2 * s) * HW] + (float)wcol;    \
      const float y = (float)(s % 3 - 1) + eob[(2 * s + 1) * HW] + (float)h;   \
      const float x0f = floorf(x), y0f = floorf(y);                            \
      const float fx0 = x - x0f, fx1 = 1.0f - fx0;                             \
      const float fy0 = y - y0f, fy1 = 1.0f - fy0;                             \
      const int x0 = (int)x0f, y0 = (int)y0f;                                  \
      const int x1 = x0 + 1,   y1 = y0 + 1;                                    \
      const bool vx0 = (unsigned)x0 < (unsigned)WW;                            \
      const bool vx1 = (unsigned)x1 < (unsigned)WW;                            \
      const bool vy0 = (unsigned)y0 < (unsigned)HH;                            \
      const bool vy1 = (unsigned)y1 < (unsigned)HH;                            \
      const float a = (vx0 && vy0) ? fx1 * fy1 : 0.0f;                         \
      const float b = (vx1 && vy0) ? fx0 * fy1 : 0.0f;                         \
      const float c2 = (vx0 && vy1) ? fx1 * fy0 : 0.0f;                        \
      const float d = (vx1 && vy1) ? fx0 * fy0 : 0.0f;                         \
      const int cx0 = min(max(x0, 0), WW - 1), cx1 = min(max(x1, 0), WW - 1);  \
      const int cy0 = min(max(y0, 0), HH - 1), cy1 = min(max(y1, 0), HH - 1);  \
      const float v = a * (RPC)[cy0 * WW + cx0] + b * (RPC)[cy0 * WW + cx1]    \
                    + c2 * (RPC)[cy1 * WW + cx0] + d * (RPC)[cy1 * WW + cx1];  \
      acc[s] += lv * v;                                                        \
    }                                                                          \
  }

__global__ __launch_bounds__(1024) void corr_kernel(
    const float* __restrict__ left, const float* __restrict__ right,
    const float* __restrict__ eo, float* __restrict__ out)
{
    __shared__ float smem[2 * BUFDW];   // 48.6 KB

    const int tid = threadIdx.x;
    const int lane = tid & 63;
    const int wv = tid >> 6;            // wave id 0..15
    const int bid = blockIdx.x;
    const int g = bid & (GG - 1);
    const int h0 = ((bid >> 3) & 15) << 2;   // h-tile base
    const int n = bid >> 7;

    const int virt_row0 = h0 - 8;                 // slot 1 maps here
    const int row0 = max(0, virt_row0);
    const int row_last = min(HH - 1, h0 + TY + 8);
    const int nrows = row_last - row0 + 1;        // <= 21
    const int sbase = row0 - virt_row0 + 1;       // first data slot

    const int hh = tid >> 8;            // 0..3
    const int h = h0 + hh;
    const int wcol = tid & 255;
    const int pix = h * WW + wcol;

    // zero both buffers (guards + never-staged edge slots must read 0.0)
    for (int i = tid; i < 2 * BUFDW; i += 1024) smem[i] = 0.0f;

    const float* eob = eo + (size_t)n * SS * 2 * HW + pix;

    int lbase[SS];
    float wA[SS], wB[SS], wC[SS], wD[SS];
    int badmask = 0;

#pragma unroll
    for (int s = 0; s < SS; ++s) {
        const float x = (float)(s / 3 - 1) + eob[(2 * s) * HW] + (float)wcol;
        const float y = (float)(s % 3 - 1) + eob[(2 * s + 1) * HW] + (float)h;
        const float x0f = floorf(x), y0f = floorf(y);
        const float fx0 = x - x0f, fx1 = 1.0f - fx0;
        const float fy0 = y - y0f, fy1 = 1.0f - fy0;
        const int x0 = (int)x0f, y0 = (int)y0f;
        const int x1 = x0 + 1,   y1 = y0 + 1;
        const bool vx0 = (unsigned)x0 < (unsigned)WW;
        const bool vx1 = (unsigned)x1 < (unsigned)WW;
        const bool vy0 = (unsigned)y0 < (unsigned)HH;
        const bool vy1 = (unsigned)y1 < (unsigned)HH;

        wA[s] = (vx0 && vy0) ? fx1 * fy1 : 0.0f;   // (x0,y0) -> +0
        wB[s] = (vx1 && vy0) ? fx0 * fy1 : 0.0f;   // (x1,y0) -> +1
        wC[s] = (vx0 && vy1) ? fx1 * fy0 : 0.0f;   // (x0,y1) -> +ROWDW
        wD[s] = (vx1 && vy1) ? fx0 * fy0 : 0.0f;   // (x1,y1) -> +ROWDW+1

        const int xc = min(max(x0, -1), WW);                 // [-1,256]
        const int rr = min(max(y0 - virt_row0 + 1, 0), NSLOT - 1); // [0,22]
        lbase[s] = (rr * ROWDW + GUARD + xc) * 4;

        // image-valid tap row outside staged window -> global fallback
        if ((vy0 && (y0 < row0 || y0 > row_last)) ||
            (vy1 && (y1 < row0 || y1 > row_last)))
            badmask |= 1 << s;
    }

    float acc[SS];
#pragma unroll
    for (int s = 0; s < SS; ++s) acc[s] = 0.0f;

    const float* lp = left  + (size_t)(n * CC + g * CG) * HW + pix;
    const float* rp = right + (size_t)(n * CC + g * CG) * HW;
    const char* sb = (const char*)smem;

    __syncthreads();                 // zero-init complete before DMA writes
    STAGE(0, rp);                    // buf0 <- channel 0
    __syncthreads();                 // drains vmcnt: buf0 ready

    const float* rpc = rp;
    for (int c = 0; c < CG; c += 2, rpc += 2 * HW) {
        STAGE(BUFDW, rpc + HW);      // buf1 <- channel c+1 (async)
        {
            const float lv = lp[(size_t)c * HW];
            COMPUTE(0, rpc);
        }
        __syncthreads();             // buf1 ready; buf0 free
        if (c + 2 < CG) { STAGE(0, rpc + 2 * HW); }   // buf0 <- c+2 (async)
        {
            const float lv = lp[(size_t)(c + 1) * HW];
            COMPUTE(BUFDW, rpc + HW);
        }
        __syncthreads();             // buf0 ready; buf1 free
    }

    float* ob = out + ((size_t)(n * GG + g) * SS) * HW + pix;
#pragma unroll
    for (int s = 0; s < SS; ++s)
        ob[s * HW] = acc[s] * (1.0f / CG);
}

extern "C" void kernel_launch(void* const* d_in, const int* in_sizes, int n_in,
                              void* d_out, int out_size, void* d_ws, size_t ws_size,
                              hipStream_t stream) {
    const float* left  = (const float*)d_in[0];
    const float* right = (const float*)d_in[1];
    const float* eo    = (const float*)d_in[2];
    float* out = (float*)d_out;
    (void)d_ws; (void)ws_size; (void)in_sizes; (void)n_in; (void)out_size;

    dim3 grid(NB * (HH / TY) * GG);   // 256 blocks: (n, h-tile, group)
    dim3 block(1024);                  // 16 waves; thread = (hh, w)
    corr_kernel<<<grid, block, 0, stream>>>(left, right, eo, out);
}